// Round 9
// baseline (953.233 us; speedup 1.0000x reference)
//
#include <hip/hip_runtime.h>

#define D 128
#define H 256
#define NBLK 512          // partition blocks
#define BUCKSH 8          // bucket = dst >> 8  (256 nodes/bucket)

typedef _Float16 half8 __attribute__((ext_vector_type(8)));
typedef _Float16 half2v __attribute__((ext_vector_type(2)));
typedef float floatx4 __attribute__((ext_vector_type(4)));

// ======== multi-block exclusive scan ========
__global__ __launch_bounds__(256) void scan_part(const int* __restrict__ cnt,
                                                 int* __restrict__ bsum, int N){
  int base = blockIdx.x*1024;
  int tid = threadIdx.x;
  int idx = base + tid*4;
  int4 v = {0,0,0,0};
  if (idx + 3 < N) v = *(const int4*)(cnt + idx);
  else {
    if (idx   < N) v.x = cnt[idx];
    if (idx+1 < N) v.y = cnt[idx+1];
    if (idx+2 < N) v.z = cnt[idx+2];
    if (idx+3 < N) v.w = cnt[idx+3];
  }
  int s = v.x + v.y + v.z + v.w;
  #pragma unroll
  for (int off = 32; off > 0; off >>= 1) s += __shfl_down(s, off, 64);
  __shared__ int ws[4];
  int lane = tid & 63, wave = tid >> 6;
  if (lane == 0) ws[wave] = s;
  __syncthreads();
  if (tid == 0) bsum[blockIdx.x] = ws[0] + ws[1] + ws[2] + ws[3];
}

__global__ __launch_bounds__(1024) void scan_bsums(const int* __restrict__ bsum,
                                                   int* __restrict__ bbase,
                                                   int* __restrict__ total_out, int nb, int N){
  __shared__ int sh[1024];
  int tid = threadIdx.x;
  int v = (tid < nb) ? bsum[tid] : 0;
  sh[tid] = v;
  __syncthreads();
  #pragma unroll
  for (int off = 1; off < 1024; off <<= 1){
    int t = 0;
    if (tid >= off) t = sh[tid - off];
    __syncthreads();
    if (tid >= off) sh[tid] += t;
    __syncthreads();
  }
  if (tid < nb) bbase[tid] = sh[tid] - v;
  if (tid == 0) total_out[N] = sh[1023];   // grand total at [N]
}

__global__ __launch_bounds__(256) void scan_emit(const int* __restrict__ cnt,
                                                 const int* __restrict__ bbase,
                                                 int* __restrict__ outp, int N){
  int base = blockIdx.x*1024;
  int tid = threadIdx.x;
  int idx = base + tid*4;
  int4 v = {0,0,0,0};
  if (idx + 3 < N) v = *(const int4*)(cnt + idx);
  else {
    if (idx   < N) v.x = cnt[idx];
    if (idx+1 < N) v.y = cnt[idx+1];
    if (idx+2 < N) v.z = cnt[idx+2];
    if (idx+3 < N) v.w = cnt[idx+3];
  }
  int s = v.x + v.y + v.z + v.w;
  int lane = tid & 63, wave = tid >> 6;
  int incl = s;
  #pragma unroll
  for (int off = 1; off < 64; off <<= 1){
    int t = __shfl_up(incl, off, 64);
    if (lane >= off) incl += t;
  }
  __shared__ int ws[4];
  if (lane == 63) ws[wave] = incl;
  __syncthreads();
  int woff = 0;
  #pragma unroll
  for (int w = 0; w < 4; ++w) if (w < wave) woff += ws[w];
  int off0 = bbase[blockIdx.x] + woff + (incl - s);
  if (idx   < N) outp[idx]   = off0;
  if (idx+1 < N) outp[idx+1] = off0 + v.x;
  if (idx+2 < N) outp[idx+2] = off0 + v.x + v.y;
  if (idx+3 < N) outp[idx+3] = off0 + v.x + v.y + v.z;
}

// ======== 3-pass CSR partition build (staged entry packed in ONE uint) ========
// staged = (dloc<<24) | (code<<20) | src ; packed = staged & 0xFFFFFF
__global__ __launch_bounds__(256) void part_count(const int* __restrict__ dst,
                                                  int* __restrict__ cntBB,
                                                  int E, int chunk, int nbuck){
  __shared__ int lc[512];
  int b = blockIdx.x;
  for (int i = threadIdx.x; i < nbuck; i += 256) lc[i] = 0;
  __syncthreads();
  int e0 = b*chunk, e1 = min(e0 + chunk, E);
  for (int e = e0 + threadIdx.x; e < e1; e += 256)
    atomicAdd(&lc[dst[e] >> BUCKSH], 1);
  __syncthreads();
  for (int i = threadIdx.x; i < nbuck; i += 256) cntBB[i*NBLK + b] = lc[i];
}

__global__ __launch_bounds__(256) void part_bin(const int* __restrict__ src,
                                                const int* __restrict__ dst,
                                                const int* __restrict__ ea,
                                                const int* __restrict__ baseBB,
                                                unsigned* __restrict__ staged,
                                                int E, int chunk, int nbuck){
  __shared__ int run[512];
  int b = blockIdx.x;
  for (int i = threadIdx.x; i < nbuck; i += 256) run[i] = baseBB[i*NBLK + b];
  __syncthreads();
  int e0 = b*chunk, e1 = min(e0 + chunk, E);
  for (int e = e0 + threadIdx.x; e < e1; e += 256){
    int d = dst[e];
    unsigned pv = ((unsigned)(d & 255) << 24) |
                  ((unsigned)(ea[2*e]*3 + ea[2*e+1]) << 20) | (unsigned)src[e];
    int pos = atomicAdd(&run[d >> BUCKSH], 1);
    staged[pos] = pv;
  }
}

__global__ __launch_bounds__(256) void part_emit(const unsigned* __restrict__ staged,
                                                 const int* __restrict__ baseBB,
                                                 unsigned* __restrict__ packed,
                                                 int* __restrict__ rowptr,
                                                 int N, int E, int nbuck, int M){
  __shared__ int ncnt[256];
  __shared__ int sscan[256];
  __shared__ int basep[256];
  __shared__ int cur[256];
  int k = blockIdx.x;
  int tid = threadIdx.x;
  int bstart = baseBB[k*NBLK];
  int bend = (k+1 < nbuck) ? baseBB[(k+1)*NBLK] : baseBB[M];
  ncnt[tid] = 0; cur[tid] = 0;
  __syncthreads();
  for (int j = bstart + tid; j < bend; j += 256)
    atomicAdd(&ncnt[staged[j] >> 24], 1);
  __syncthreads();
  int v = ncnt[tid];
  sscan[tid] = v;
  __syncthreads();
  #pragma unroll
  for (int off = 1; off < 256; off <<= 1){
    int t = (tid >= off) ? sscan[tid-off] : 0;
    __syncthreads();
    sscan[tid] += t;
    __syncthreads();
  }
  int excl = sscan[tid] - v;
  basep[tid] = bstart + excl;
  int node = k*256 + tid;
  if (node < N) rowptr[node] = bstart + excl;
  if (k == nbuck-1 && tid == 0) rowptr[N] = E;
  __syncthreads();
  for (int j = bstart + tid; j < bend; j += 256){
    unsigned s = staged[j];
    int dloc = (int)(s >> 24);
    int pos = basep[dloc] + atomicAdd(&cur[dloc], 1);
    packed[pos] = s & 0xFFFFFFu;
  }
}

// ---------------- input embedding (fp16 h) ----------------
__global__ void embed_kernel(const int* __restrict__ x, const float* __restrict__ xemb,
                             _Float16* __restrict__ h, int N){
  int t = blockIdx.x*256 + threadIdx.x;
  if (t >= N*16) return;
  int n = t >> 4, c = (t & 15) * 8;
  int x0 = x[2*n], x1 = x[2*n+1];
  const float* r0 = xemb + (size_t)x0*D + c;
  const float* r1 = xemb + (size_t)(120 + x1)*D + c;
  half8 o;
  #pragma unroll
  for (int j = 0; j < 8; ++j) o[j] = (_Float16)(r0[j] + r1[j]);
  *(half8*)(h + (size_t)n*D + c) = o;
}

// ---------------- per-layer constant tables ----------------
__global__ void prep_tables(const float* __restrict__ etab, const float* __restrict__ gamma,
                            const float* __restrict__ beta, const float* __restrict__ mean,
                            const float* __restrict__ var, const float* __restrict__ b2,
                            float* __restrict__ comb, float* __restrict__ sc, float* __restrict__ sh){
  int l = blockIdx.x, d = threadIdx.x;
  const float* et = etab + (size_t)l*9*D;
  float* cl = comb + (size_t)l*10*D;
  #pragma unroll
  for (int b = 0; b < 3; ++b)
    #pragma unroll
    for (int dd = 0; dd < 3; ++dd)
      cl[(b*3+dd)*D + d] = et[b*D + d] + et[(6+dd)*D + d];
  cl[9*D + d] = et[4*D + d] + et[6*D + d];
  float A = gamma[l*D+d] * rsqrtf(var[l*D+d] + 1e-5f);
  sc[l*D+d] = A;
  sh[l*D+d] = (b2[l*D+d] - mean[l*D+d]) * A + beta[l*D+d];
}

// repack weights fragment-major for coalesced B loads
__global__ void repack_weights(const float* __restrict__ w1, const float* __restrict__ w2,
                               _Float16* __restrict__ w1f, _Float16* __restrict__ w2f, int total){
  int i = blockIdx.x*256 + threadIdx.x;
  if (i >= total) return;                 // total = 5*H*D
  int l = i / (H*D), r = i % (H*D);
  {
    int n = r / D, k = r % D;
    w1f[(size_t)l*H*D + (size_t)(k>>3)*(H*8) + n*8 + (k&7)] = (_Float16)w1[i];
  }
  {
    int n2 = r / H, k2 = r % H;
    w2f[(size_t)l*D*H + (size_t)(k2>>3)*(D*8) + n2*8 + (k2&7)] = (_Float16)w2[i];
  }
}

// ---------------- aggregation: one wave per node, fp16, 16 gathers in flight ----------------
// (R8 shape — scalarized packed loads, ~81% of random-gather ceiling; DO NOT TOUCH)
__global__ __launch_bounds__(256) void agg_kernel(
    const _Float16* __restrict__ h, const unsigned* __restrict__ packed,
    const int* __restrict__ rowptr, const float* __restrict__ comb,
    _Float16* __restrict__ agg, int N){
  __shared__ float cl[10*D];
  int tid = threadIdx.x;
  for (int i = tid; i < 10*D; i += 256) cl[i] = comb[i];
  __syncthreads();
  int node = __builtin_amdgcn_readfirstlane(blockIdx.x*4 + (tid >> 6)); // wave-uniform
  if (node >= N) return;
  int lane = tid & 63;
  int c = lane * 2;
  half2v hv = *(const half2v*)(h + (size_t)node*D + c);
  float ax = (float)hv.x + cl[9*D + c];
  float ay = (float)hv.y + cl[9*D + c + 1];
  int beg = rowptr[node], end = rowptr[node+1];
  unsigned long long cp = 0;             // 9 codes x 7-bit counters
  for (int j = beg; j < end; j += 16){
    int m = end - j;                     // wave-uniform
    unsigned p[16];
    #pragma unroll
    for (int k = 0; k < 16; ++k) if (k < m) p[k] = packed[j+k];
    half2v v[16];
    #pragma unroll
    for (int k = 0; k < 16; ++k) if (k < m)
      v[k] = *(const half2v*)(h + (size_t)(p[k] & 0xFFFFFu)*D + c);
    #pragma unroll
    for (int k = 0; k < 16; ++k) if (k < m){
      cp += 1ULL << (7*(int)(p[k] >> 20));
      ax += (float)v[k].x;
      ay += (float)v[k].y;
    }
  }
  #pragma unroll
  for (int cd = 0; cd < 9; ++cd){
    float cnt = (float)(int)((cp >> (7*cd)) & 127);
    ax += cnt * cl[cd*D + c];
    ay += cnt * cl[cd*D + c + 1];
  }
  half2v o; o.x = (_Float16)ax; o.y = (_Float16)ay;
  *(half2v*)(agg + (size_t)node*D + c) = o;
}

// ---------------- fused GIN MLP, 128-row tile: A->LDS, GEMM1+ReLU -> GEMM2+BN --------
// 256 thr / 4 waves; each wave covers all 128 rows (mt=8). LDS: atile 32 KB aliased in
// hmid 64 KB -> 2 blocks/CU. B re-reads per row halved vs 64-row tile.
__global__ __launch_bounds__(256) void mlp_kernel(
    const _Float16* __restrict__ agg, const _Float16* __restrict__ w1f,
    const _Float16* __restrict__ w2f, const float* __restrict__ b1,
    const float* __restrict__ sc, const float* __restrict__ sh,
    _Float16* __restrict__ hout, float* __restrict__ fout,
    int N, int relu_out){
  __shared__ __align__(16) char smem[128*256*2];
  _Float16* atile = (_Float16*)smem;   // row*128 + (c8 ^ (row&15))*8 + (col&7)
  _Float16* hmid  = (_Float16*)smem;   // row*256 + (c8 ^ (row&31))*8 + (col&7)
  int tid = threadIdx.x;
  int wave = tid >> 6, lane = tid & 63;
  int quad = lane >> 4, l15 = lane & 15;
  int r0 = blockIdx.x * 128;

  half8 zf;
  #pragma unroll
  for (int j = 0; j < 8; ++j) zf[j] = (_Float16)0.f;

  // ---- stage A tile [128x128] -> LDS, XOR-swizzled 16B chunks
  #pragma unroll
  for (int i = 0; i < 8; ++i){
    int ci = i*256 + tid;            // 2048 chunks
    int row = ci >> 4, c8 = ci & 15;
    int m = r0 + row;
    half8 v = (m < N) ? *(const half8*)(agg + (size_t)m*D + c8*8) : zf;
    *(half8*)(atile + row*128 + ((c8 ^ (row & 15)) * 8)) = v;
  }
  __syncthreads();

  // ---- GEMM1: C1[128,256] = A x W1^T ; wave owns cols [64w,64w+64)
  floatx4 acc[8][4] = {};
  half8 bcur[4], bnxt[4];
  #pragma unroll
  for (int nt = 0; nt < 4; ++nt)
    bcur[nt] = *(const half8*)(w1f + (size_t)quad*(H*8) + (wave*64 + nt*16 + l15)*8);
  #pragma unroll
  for (int ks = 0; ks < 4; ++ks){
    if (ks < 3){
      #pragma unroll
      for (int nt = 0; nt < 4; ++nt)
        bnxt[nt] = *(const half8*)(w1f + (size_t)((ks+1)*4 + quad)*(H*8) + (wave*64 + nt*16 + l15)*8);
    }
    int c8 = ks*4 + quad;
    #pragma unroll
    for (int mt = 0; mt < 8; ++mt){
      int row = mt*16 + l15;
      half8 af = *(const half8*)(atile + row*128 + ((c8 ^ (row & 15)) * 8));
      #pragma unroll
      for (int nt = 0; nt < 4; ++nt)
        acc[mt][nt] = __builtin_amdgcn_mfma_f32_16x16x32_f16(af, bcur[nt], acc[mt][nt], 0, 0, 0);
    }
    #pragma unroll
    for (int nt = 0; nt < 4; ++nt) bcur[nt] = bnxt[nt];
  }

  // prefetch GEMM2's first B-frags NOW so L2 latency hides under epilogue-1 + barrier
  half8 gcur[2], gnxt[2];
  #pragma unroll
  for (int nt = 0; nt < 2; ++nt)
    gcur[nt] = *(const half8*)(w2f + (size_t)quad*(D*8) + (wave*32 + nt*16 + l15)*8);

  __syncthreads();   // all waves done reading atile before hmid overwrites it

  // epilogue 1: +b1, ReLU -> hmid (swizzled)
  #pragma unroll
  for (int nt = 0; nt < 4; ++nt){
    int n = wave*64 + nt*16 + l15;
    float bias = b1[n];
    #pragma unroll
    for (int mt = 0; mt < 8; ++mt)
      #pragma unroll
      for (int r = 0; r < 4; ++r){
        int row = mt*16 + quad*4 + r;   // C/D layout: col=lane&15, row=quad*4+reg
        hmid[row*256 + (((n >> 3) ^ (row & 31)) * 8) + (n & 7)] =
            (_Float16)fmaxf(acc[mt][nt][r] + bias, 0.f);
      }
  }
  __syncthreads();

  // ---- GEMM2: C2[128,128] = hmid x W2^T ; wave owns cols [32w,32w+32)
  floatx4 acc2[8][2] = {};
  #pragma unroll
  for (int ks = 0; ks < 8; ++ks){
    if (ks < 7){
      #pragma unroll
      for (int nt = 0; nt < 2; ++nt)
        gnxt[nt] = *(const half8*)(w2f + (size_t)((ks+1)*4 + quad)*(D*8) + (wave*32 + nt*16 + l15)*8);
    }
    int c8 = ks*4 + quad;
    #pragma unroll
    for (int mt = 0; mt < 8; ++mt){
      int row = mt*16 + l15;
      half8 af = *(const half8*)(hmid + row*256 + ((c8 ^ (row & 31)) * 8));
      #pragma unroll
      for (int nt = 0; nt < 2; ++nt)
        acc2[mt][nt] = __builtin_amdgcn_mfma_f32_16x16x32_f16(af, gcur[nt], acc2[mt][nt], 0, 0, 0);
    }
    #pragma unroll
    for (int nt = 0; nt < 2; ++nt) gcur[nt] = gnxt[nt];
  }

  // epilogue 2: BN (folded b2), optional ReLU, store
  #pragma unroll
  for (int nt = 0; nt < 2; ++nt){
    int n = wave*32 + nt*16 + l15;
    float A = sc[n], B = sh[n];
    #pragma unroll
    for (int mt = 0; mt < 8; ++mt)
      #pragma unroll
      for (int r = 0; r < 4; ++r){
        int row = r0 + mt*16 + quad*4 + r;
        if (row < N){
          float v = acc2[mt][nt][r]*A + B;
          if (relu_out) v = fmaxf(v, 0.f);
          if (fout) fout[(size_t)row*D + n] = v;
          else      hout[(size_t)row*D + n] = (_Float16)v;
        }
      }
  }
}

extern "C" void kernel_launch(void* const* d_in, const int* in_sizes, int n_in,
                              void* d_out, int out_size, void* d_ws, size_t ws_size,
                              hipStream_t stream){
  const int*   x     = (const int*)d_in[0];
  const int*   ei    = (const int*)d_in[1];
  const int*   ea    = (const int*)d_in[2];
  const float* xemb  = (const float*)d_in[3];
  const float* etab  = (const float*)d_in[4];
  const float* w1    = (const float*)d_in[5];
  const float* b1    = (const float*)d_in[6];
  const float* w2    = (const float*)d_in[7];
  const float* b2    = (const float*)d_in[8];
  const float* gamma = (const float*)d_in[9];
  const float* beta  = (const float*)d_in[10];
  const float* mean  = (const float*)d_in[11];
  const float* var   = (const float*)d_in[12];
  float* out = (float*)d_out;

  int N = in_sizes[0] / 2;
  int E = in_sizes[1] / 2;
  int nbuck = (N + 255) >> 8;
  int M = nbuck * NBLK;
  int nbM = (M + 1023) / 1024;
  int chunk = (E + NBLK - 1) / NBLK;

  char* ws = (char*)d_ws;
  size_t off = 0;
  auto alloc = [&](size_t b){ void* p = ws + off; off += (b + 255) & ~(size_t)255; return p; };
  _Float16* h      = (_Float16*)alloc((size_t)N*D*2);
  _Float16* agg    = (_Float16*)alloc((size_t)N*D*2);    // staged aliases this (E*4 <= N*D*2)
  unsigned* packed = (unsigned*)alloc((size_t)(E+16)*4);
  int*      rowptr = (int*)alloc((size_t)(N+1)*4);
  int*      cntBB  = (int*)alloc((size_t)M*4);
  int*      baseBB = (int*)alloc((size_t)(M+1)*4);
  int*      bsum   = (int*)alloc((size_t)nbM*4);
  int*      bbase  = (int*)alloc((size_t)nbM*4);
  _Float16* w1f    = (_Float16*)alloc((size_t)5*H*D*2);
  _Float16* w2f    = (_Float16*)alloc((size_t)5*D*H*2);
  float*    comb   = (float*)alloc((size_t)5*10*D*4);
  float*    sc     = (float*)alloc((size_t)5*D*4);
  float*    sh     = (float*)alloc((size_t)5*D*4);
  unsigned* staged = (unsigned*)agg;   // dead before agg_kernel first writes agg

  const int* srcp = ei;
  const int* dstp = ei + E;

  part_count<<<NBLK, 256, 0, stream>>>(dstp, cntBB, E, chunk, nbuck);
  scan_part <<<nbM, 256, 0, stream>>>(cntBB, bsum, M);
  scan_bsums<<<1, 1024, 0, stream>>>(bsum, bbase, baseBB, nbM, M);   // baseBB[M] = E
  scan_emit <<<nbM, 256, 0, stream>>>(cntBB, bbase, baseBB, M);
  part_bin  <<<NBLK, 256, 0, stream>>>(srcp, dstp, ea, baseBB, staged, E, chunk, nbuck);
  part_emit <<<nbuck, 256, 0, stream>>>(staged, baseBB, packed, rowptr, N, E, nbuck, M);
  repack_weights<<<(5*H*D+255)/256, 256, 0, stream>>>(w1, w2, w1f, w2f, 5*H*D);
  prep_tables<<<5, 128, 0, stream>>>(etab, gamma, beta, mean, var, b2, comb, sc, sh);
  embed_kernel<<<((size_t)N*16+255)/256, 256, 0, stream>>>(x, xemb, h, N);

  for (int l = 0; l < 5; ++l){
    agg_kernel<<<(N+3)/4, 256, 0, stream>>>(h, packed, rowptr, comb + (size_t)l*10*D, agg, N);
    int last = (l == 4);
    mlp_kernel<<<(N+127)/128, 256, 0, stream>>>(agg, w1f + (size_t)l*H*D, w2f + (size_t)l*D*H,
        b1 + (size_t)l*H, sc + (size_t)l*D, sh + (size_t)l*D,
        last ? (_Float16*)nullptr : h, last ? out : (float*)nullptr,
        N, last ? 0 : 1);
  }
}

// Round 10
// 754.619 us; speedup vs baseline: 1.2632x; 1.2632x over previous
//
#include <hip/hip_runtime.h>

#define D 128
#define H 256
#define NBLK 512          // partition blocks
#define BUCKSH 8          // bucket = dst >> 8  (256 nodes/bucket)

typedef _Float16 half8 __attribute__((ext_vector_type(8)));
typedef _Float16 half2v __attribute__((ext_vector_type(2)));
typedef float floatx4 __attribute__((ext_vector_type(4)));

// ======== multi-block exclusive scan ========
__global__ __launch_bounds__(256) void scan_part(const int* __restrict__ cnt,
                                                 int* __restrict__ bsum, int N){
  int base = blockIdx.x*1024;
  int tid = threadIdx.x;
  int idx = base + tid*4;
  int4 v = {0,0,0,0};
  if (idx + 3 < N) v = *(const int4*)(cnt + idx);
  else {
    if (idx   < N) v.x = cnt[idx];
    if (idx+1 < N) v.y = cnt[idx+1];
    if (idx+2 < N) v.z = cnt[idx+2];
    if (idx+3 < N) v.w = cnt[idx+3];
  }
  int s = v.x + v.y + v.z + v.w;
  #pragma unroll
  for (int off = 32; off > 0; off >>= 1) s += __shfl_down(s, off, 64);
  __shared__ int ws[4];
  int lane = tid & 63, wave = tid >> 6;
  if (lane == 0) ws[wave] = s;
  __syncthreads();
  if (tid == 0) bsum[blockIdx.x] = ws[0] + ws[1] + ws[2] + ws[3];
}

__global__ __launch_bounds__(1024) void scan_bsums(const int* __restrict__ bsum,
                                                   int* __restrict__ bbase,
                                                   int* __restrict__ total_out, int nb, int N){
  __shared__ int sh[1024];
  int tid = threadIdx.x;
  int v = (tid < nb) ? bsum[tid] : 0;
  sh[tid] = v;
  __syncthreads();
  #pragma unroll
  for (int off = 1; off < 1024; off <<= 1){
    int t = 0;
    if (tid >= off) t = sh[tid - off];
    __syncthreads();
    if (tid >= off) sh[tid] += t;
    __syncthreads();
  }
  if (tid < nb) bbase[tid] = sh[tid] - v;
  if (tid == 0) total_out[N] = sh[1023];   // grand total at [N]
}

__global__ __launch_bounds__(256) void scan_emit(const int* __restrict__ cnt,
                                                 const int* __restrict__ bbase,
                                                 int* __restrict__ outp, int N){
  int base = blockIdx.x*1024;
  int tid = threadIdx.x;
  int idx = base + tid*4;
  int4 v = {0,0,0,0};
  if (idx + 3 < N) v = *(const int4*)(cnt + idx);
  else {
    if (idx   < N) v.x = cnt[idx];
    if (idx+1 < N) v.y = cnt[idx+1];
    if (idx+2 < N) v.z = cnt[idx+2];
    if (idx+3 < N) v.w = cnt[idx+3];
  }
  int s = v.x + v.y + v.z + v.w;
  int lane = tid & 63, wave = tid >> 6;
  int incl = s;
  #pragma unroll
  for (int off = 1; off < 64; off <<= 1){
    int t = __shfl_up(incl, off, 64);
    if (lane >= off) incl += t;
  }
  __shared__ int ws[4];
  if (lane == 63) ws[wave] = incl;
  __syncthreads();
  int woff = 0;
  #pragma unroll
  for (int w = 0; w < 4; ++w) if (w < wave) woff += ws[w];
  int off0 = bbase[blockIdx.x] + woff + (incl - s);
  if (idx   < N) outp[idx]   = off0;
  if (idx+1 < N) outp[idx+1] = off0 + v.x;
  if (idx+2 < N) outp[idx+2] = off0 + v.x + v.y;
  if (idx+3 < N) outp[idx+3] = off0 + v.x + v.y + v.z;
}

// ======== 3-pass CSR partition build (staged entry packed in ONE uint) ========
// staged = (dloc<<24) | (code<<20) | src ; packed = staged & 0xFFFFFF
__global__ __launch_bounds__(256) void part_count(const int* __restrict__ dst,
                                                  int* __restrict__ cntBB,
                                                  int E, int chunk, int nbuck){
  __shared__ int lc[512];
  int b = blockIdx.x;
  for (int i = threadIdx.x; i < nbuck; i += 256) lc[i] = 0;
  __syncthreads();
  int e0 = b*chunk, e1 = min(e0 + chunk, E);
  for (int e = e0 + threadIdx.x; e < e1; e += 256)
    atomicAdd(&lc[dst[e] >> BUCKSH], 1);
  __syncthreads();
  for (int i = threadIdx.x; i < nbuck; i += 256) cntBB[i*NBLK + b] = lc[i];
}

__global__ __launch_bounds__(256) void part_bin(const int* __restrict__ src,
                                                const int* __restrict__ dst,
                                                const int* __restrict__ ea,
                                                const int* __restrict__ baseBB,
                                                unsigned* __restrict__ staged,
                                                int E, int chunk, int nbuck){
  __shared__ int run[512];
  int b = blockIdx.x;
  for (int i = threadIdx.x; i < nbuck; i += 256) run[i] = baseBB[i*NBLK + b];
  __syncthreads();
  int e0 = b*chunk, e1 = min(e0 + chunk, E);
  for (int e = e0 + threadIdx.x; e < e1; e += 256){
    int d = dst[e];
    unsigned pv = ((unsigned)(d & 255) << 24) |
                  ((unsigned)(ea[2*e]*3 + ea[2*e+1]) << 20) | (unsigned)src[e];
    int pos = atomicAdd(&run[d >> BUCKSH], 1);
    staged[pos] = pv;
  }
}

__global__ __launch_bounds__(256) void part_emit(const unsigned* __restrict__ staged,
                                                 const int* __restrict__ baseBB,
                                                 unsigned* __restrict__ packed,
                                                 int* __restrict__ rowptr,
                                                 int N, int E, int nbuck, int M){
  __shared__ int ncnt[256];
  __shared__ int sscan[256];
  __shared__ int basep[256];
  __shared__ int cur[256];
  int k = blockIdx.x;
  int tid = threadIdx.x;
  int bstart = baseBB[k*NBLK];
  int bend = (k+1 < nbuck) ? baseBB[(k+1)*NBLK] : baseBB[M];
  ncnt[tid] = 0; cur[tid] = 0;
  __syncthreads();
  for (int j = bstart + tid; j < bend; j += 256)
    atomicAdd(&ncnt[staged[j] >> 24], 1);
  __syncthreads();
  int v = ncnt[tid];
  sscan[tid] = v;
  __syncthreads();
  #pragma unroll
  for (int off = 1; off < 256; off <<= 1){
    int t = (tid >= off) ? sscan[tid-off] : 0;
    __syncthreads();
    sscan[tid] += t;
    __syncthreads();
  }
  int excl = sscan[tid] - v;
  basep[tid] = bstart + excl;
  int node = k*256 + tid;
  if (node < N) rowptr[node] = bstart + excl;
  if (k == nbuck-1 && tid == 0) rowptr[N] = E;
  __syncthreads();
  for (int j = bstart + tid; j < bend; j += 256){
    unsigned s = staged[j];
    int dloc = (int)(s >> 24);
    int pos = basep[dloc] + atomicAdd(&cur[dloc], 1);
    packed[pos] = s & 0xFFFFFFu;
  }
}

// ---------------- input embedding (fp16 h) ----------------
__global__ void embed_kernel(const int* __restrict__ x, const float* __restrict__ xemb,
                             _Float16* __restrict__ h, int N){
  int t = blockIdx.x*256 + threadIdx.x;
  if (t >= N*16) return;
  int n = t >> 4, c = (t & 15) * 8;
  int x0 = x[2*n], x1 = x[2*n+1];
  const float* r0 = xemb + (size_t)x0*D + c;
  const float* r1 = xemb + (size_t)(120 + x1)*D + c;
  half8 o;
  #pragma unroll
  for (int j = 0; j < 8; ++j) o[j] = (_Float16)(r0[j] + r1[j]);
  *(half8*)(h + (size_t)n*D + c) = o;
}

// ---------------- per-layer constant tables ----------------
__global__ void prep_tables(const float* __restrict__ etab, const float* __restrict__ gamma,
                            const float* __restrict__ beta, const float* __restrict__ mean,
                            const float* __restrict__ var, const float* __restrict__ b2,
                            float* __restrict__ comb, float* __restrict__ sc, float* __restrict__ sh){
  int l = blockIdx.x, d = threadIdx.x;
  const float* et = etab + (size_t)l*9*D;
  float* cl = comb + (size_t)l*10*D;
  #pragma unroll
  for (int b = 0; b < 3; ++b)
    #pragma unroll
    for (int dd = 0; dd < 3; ++dd)
      cl[(b*3+dd)*D + d] = et[b*D + d] + et[(6+dd)*D + d];
  cl[9*D + d] = et[4*D + d] + et[6*D + d];
  float A = gamma[l*D+d] * rsqrtf(var[l*D+d] + 1e-5f);
  sc[l*D+d] = A;
  sh[l*D+d] = (b2[l*D+d] - mean[l*D+d]) * A + beta[l*D+d];
}

// repack weights fragment-major for coalesced B loads
__global__ void repack_weights(const float* __restrict__ w1, const float* __restrict__ w2,
                               _Float16* __restrict__ w1f, _Float16* __restrict__ w2f, int total){
  int i = blockIdx.x*256 + threadIdx.x;
  if (i >= total) return;                 // total = 5*H*D
  int l = i / (H*D), r = i % (H*D);
  {
    int n = r / D, k = r % D;
    w1f[(size_t)l*H*D + (size_t)(k>>3)*(H*8) + n*8 + (k&7)] = (_Float16)w1[i];
  }
  {
    int n2 = r / H, k2 = r % H;
    w2f[(size_t)l*D*H + (size_t)(k2>>3)*(D*8) + n2*8 + (k2&7)] = (_Float16)w2[i];
  }
}

// ---------------- aggregation: one wave per node, fp16, 16 gathers in flight ----------------
// (R8 shape — scalarized packed loads, ~81% of random-gather ceiling; DO NOT TOUCH)
__global__ __launch_bounds__(256) void agg_kernel(
    const _Float16* __restrict__ h, const unsigned* __restrict__ packed,
    const int* __restrict__ rowptr, const float* __restrict__ comb,
    _Float16* __restrict__ agg, int N){
  __shared__ float cl[10*D];
  int tid = threadIdx.x;
  for (int i = tid; i < 10*D; i += 256) cl[i] = comb[i];
  __syncthreads();
  int node = __builtin_amdgcn_readfirstlane(blockIdx.x*4 + (tid >> 6)); // wave-uniform
  if (node >= N) return;
  int lane = tid & 63;
  int c = lane * 2;
  half2v hv = *(const half2v*)(h + (size_t)node*D + c);
  float ax = (float)hv.x + cl[9*D + c];
  float ay = (float)hv.y + cl[9*D + c + 1];
  int beg = rowptr[node], end = rowptr[node+1];
  unsigned long long cp = 0;             // 9 codes x 7-bit counters
  for (int j = beg; j < end; j += 16){
    int m = end - j;                     // wave-uniform
    unsigned p[16];
    #pragma unroll
    for (int k = 0; k < 16; ++k) if (k < m) p[k] = packed[j+k];
    half2v v[16];
    #pragma unroll
    for (int k = 0; k < 16; ++k) if (k < m)
      v[k] = *(const half2v*)(h + (size_t)(p[k] & 0xFFFFFu)*D + c);
    #pragma unroll
    for (int k = 0; k < 16; ++k) if (k < m){
      cp += 1ULL << (7*(int)(p[k] >> 20));
      ax += (float)v[k].x;
      ay += (float)v[k].y;
    }
  }
  #pragma unroll
  for (int cd = 0; cd < 9; ++cd){
    float cnt = (float)(int)((cp >> (7*cd)) & 127);
    ax += cnt * cl[cd*D + c];
    ay += cnt * cl[cd*D + c + 1];
  }
  half2v o; o.x = (_Float16)ax; o.y = (_Float16)ay;
  *(half2v*)(agg + (size_t)node*D + c) = o;
}

// ---------------- fused GIN MLP (R8 64-row shape): A->LDS(swizzled), GEMM1+ReLU -> GEMM2+BN
__global__ __launch_bounds__(256) void mlp_kernel(
    const _Float16* __restrict__ agg, const _Float16* __restrict__ w1f,
    const _Float16* __restrict__ w2f, const float* __restrict__ b1,
    const float* __restrict__ sc, const float* __restrict__ sh,
    _Float16* __restrict__ hout, float* __restrict__ fout,
    int N, int relu_out){
  __shared__ __align__(16) char smem[64*256*2];
  _Float16* atile = (_Float16*)smem;   // row*128 + (c8 ^ (row&15))*8 + (col&7)
  _Float16* hmid  = (_Float16*)smem;   // row*256 + (c8 ^ (row&31))*8 + (col&7)
  int tid = threadIdx.x;
  int wave = tid >> 6, lane = tid & 63;
  int quad = lane >> 4, l15 = lane & 15;
  int r0 = blockIdx.x * 64;

  half8 zf;
  #pragma unroll
  for (int j = 0; j < 8; ++j) zf[j] = (_Float16)0.f;

  #pragma unroll
  for (int i = 0; i < 4; ++i){
    int ci = i*256 + tid;
    int row = ci >> 4, c8 = ci & 15;
    int m = r0 + row;
    half8 v = (m < N) ? *(const half8*)(agg + (size_t)m*D + c8*8) : zf;
    *(half8*)(atile + row*128 + ((c8 ^ (row & 15)) * 8)) = v;
  }
  __syncthreads();

  floatx4 acc[4][4] = {};
  half8 bcur[4], bnxt[4];
  #pragma unroll
  for (int nt = 0; nt < 4; ++nt)
    bcur[nt] = *(const half8*)(w1f + (size_t)quad*(H*8) + (wave*64 + nt*16 + l15)*8);
  #pragma unroll
  for (int ks = 0; ks < 4; ++ks){
    if (ks < 3){
      #pragma unroll
      for (int nt = 0; nt < 4; ++nt)
        bnxt[nt] = *(const half8*)(w1f + (size_t)((ks+1)*4 + quad)*(H*8) + (wave*64 + nt*16 + l15)*8);
    }
    int c8 = ks*4 + quad;
    half8 af[4];
    #pragma unroll
    for (int mt = 0; mt < 4; ++mt)
      af[mt] = *(const half8*)(atile + (mt*16 + l15)*128 + ((c8 ^ l15) * 8));
    #pragma unroll
    for (int mt = 0; mt < 4; ++mt)
      #pragma unroll
      for (int nt = 0; nt < 4; ++nt)
        acc[mt][nt] = __builtin_amdgcn_mfma_f32_16x16x32_f16(af[mt], bcur[nt], acc[mt][nt], 0, 0, 0);
    #pragma unroll
    for (int nt = 0; nt < 4; ++nt) bcur[nt] = bnxt[nt];
  }
  __syncthreads();

  #pragma unroll
  for (int nt = 0; nt < 4; ++nt){
    int n = wave*64 + nt*16 + l15;
    float bias = b1[n];
    #pragma unroll
    for (int mt = 0; mt < 4; ++mt)
      #pragma unroll
      for (int r = 0; r < 4; ++r){
        int row = mt*16 + quad*4 + r;
        hmid[row*256 + (((n >> 3) ^ (row & 31)) * 8) + (n & 7)] =
            (_Float16)fmaxf(acc[mt][nt][r] + bias, 0.f);
      }
  }
  __syncthreads();

  floatx4 acc2[4][2] = {};
  half8 gcur[2], gnxt[2];
  #pragma unroll
  for (int nt = 0; nt < 2; ++nt)
    gcur[nt] = *(const half8*)(w2f + (size_t)quad*(D*8) + (wave*32 + nt*16 + l15)*8);
  #pragma unroll
  for (int ks = 0; ks < 8; ++ks){
    if (ks < 7){
      #pragma unroll
      for (int nt = 0; nt < 2; ++nt)
        gnxt[nt] = *(const half8*)(w2f + (size_t)((ks+1)*4 + quad)*(D*8) + (wave*32 + nt*16 + l15)*8);
    }
    int c8 = ks*4 + quad;
    half8 af[4];
    #pragma unroll
    for (int mt = 0; mt < 4; ++mt){
      int row = mt*16 + l15;
      af[mt] = *(const half8*)(hmid + row*256 + ((c8 ^ (row & 31)) * 8));
    }
    #pragma unroll
    for (int mt = 0; mt < 4; ++mt)
      #pragma unroll
      for (int nt = 0; nt < 2; ++nt)
        acc2[mt][nt] = __builtin_amdgcn_mfma_f32_16x16x32_f16(af[mt], gcur[nt], acc2[mt][nt], 0, 0, 0);
    #pragma unroll
    for (int nt = 0; nt < 2; ++nt) gcur[nt] = gnxt[nt];
  }

  #pragma unroll
  for (int nt = 0; nt < 2; ++nt){
    int n = wave*32 + nt*16 + l15;
    float A = sc[n], B = sh[n];
    #pragma unroll
    for (int mt = 0; mt < 4; ++mt)
      #pragma unroll
      for (int r = 0; r < 4; ++r){
        int row = r0 + mt*16 + quad*4 + r;
        if (row < N){
          float v = acc2[mt][nt][r]*A + B;
          if (relu_out) v = fmaxf(v, 0.f);
          if (fout) fout[(size_t)row*D + n] = v;
          else      hout[(size_t)row*D + n] = (_Float16)v;
        }
      }
  }
}

extern "C" void kernel_launch(void* const* d_in, const int* in_sizes, int n_in,
                              void* d_out, int out_size, void* d_ws, size_t ws_size,
                              hipStream_t stream){
  const int*   x     = (const int*)d_in[0];
  const int*   ei    = (const int*)d_in[1];
  const int*   ea    = (const int*)d_in[2];
  const float* xemb  = (const float*)d_in[3];
  const float* etab  = (const float*)d_in[4];
  const float* w1    = (const float*)d_in[5];
  const float* b1    = (const float*)d_in[6];
  const float* w2    = (const float*)d_in[7];
  const float* b2    = (const float*)d_in[8];
  const float* gamma = (const float*)d_in[9];
  const float* beta  = (const float*)d_in[10];
  const float* mean  = (const float*)d_in[11];
  const float* var   = (const float*)d_in[12];
  float* out = (float*)d_out;

  int N = in_sizes[0] / 2;
  int E = in_sizes[1] / 2;
  int nbuck = (N + 255) >> 8;
  int M = nbuck * NBLK;
  int nbM = (M + 1023) / 1024;
  int chunk = (E + NBLK - 1) / NBLK;

  char* ws = (char*)d_ws;
  size_t off = 0;
  auto alloc = [&](size_t b){ void* p = ws + off; off += (b + 255) & ~(size_t)255; return p; };
  _Float16* h      = (_Float16*)alloc((size_t)N*D*2);
  _Float16* agg    = (_Float16*)alloc((size_t)N*D*2);    // staged aliases this (E*4 <= N*D*2)
  unsigned* packed = (unsigned*)alloc((size_t)(E+16)*4);
  int*      rowptr = (int*)alloc((size_t)(N+1)*4);
  int*      cntBB  = (int*)alloc((size_t)M*4);
  int*      baseBB = (int*)alloc((size_t)(M+1)*4);
  int*      bsum   = (int*)alloc((size_t)nbM*4);
  int*      bbase  = (int*)alloc((size_t)nbM*4);
  _Float16* w1f    = (_Float16*)alloc((size_t)5*H*D*2);
  _Float16* w2f    = (_Float16*)alloc((size_t)5*D*H*2);
  float*    comb   = (float*)alloc((size_t)5*10*D*4);
  float*    sc     = (float*)alloc((size_t)5*D*4);
  float*    sh     = (float*)alloc((size_t)5*D*4);
  unsigned* staged = (unsigned*)agg;   // dead before agg_kernel first writes agg

  const int* srcp = ei;
  const int* dstp = ei + E;

  part_count<<<NBLK, 256, 0, stream>>>(dstp, cntBB, E, chunk, nbuck);
  scan_part <<<nbM, 256, 0, stream>>>(cntBB, bsum, M);
  scan_bsums<<<1, 1024, 0, stream>>>(bsum, bbase, baseBB, nbM, M);   // baseBB[M] = E
  scan_emit <<<nbM, 256, 0, stream>>>(cntBB, bbase, baseBB, M);
  part_bin  <<<NBLK, 256, 0, stream>>>(srcp, dstp, ea, baseBB, staged, E, chunk, nbuck);
  part_emit <<<nbuck, 256, 0, stream>>>(staged, baseBB, packed, rowptr, N, E, nbuck, M);
  repack_weights<<<(5*H*D+255)/256, 256, 0, stream>>>(w1, w2, w1f, w2f, 5*H*D);
  prep_tables<<<5, 128, 0, stream>>>(etab, gamma, beta, mean, var, b2, comb, sc, sh);
  embed_kernel<<<((size_t)N*16+255)/256, 256, 0, stream>>>(x, xemb, h, N);

  for (int l = 0; l < 5; ++l){
    agg_kernel<<<(N+3)/4, 256, 0, stream>>>(h, packed, rowptr, comb + (size_t)l*10*D, agg, N);
    int last = (l == 4);
    mlp_kernel<<<(N+63)/64, 256, 0, stream>>>(agg, w1f + (size_t)l*H*D, w2f + (size_t)l*D*H,
        b1 + (size_t)l*H, sc + (size_t)l*D, sh + (size_t)l*D,
        last ? (_Float16*)nullptr : h, last ? out : (float*)nullptr,
        N, last ? 0 : 1);
  }
}